// Round 8
// baseline (422.842 us; speedup 1.0000x reference)
//
#include <hip/hip_runtime.h>
#include <hip/hip_bf16.h>

#define D 128  // feature dim (D_IN == D_HID == 128)
#define DD (128 * 128)

typedef float f32x4 __attribute__((ext_vector_type(4)));
typedef __bf16 bf16x8 __attribute__((ext_vector_type(8)));

__device__ __forceinline__ unsigned short f2bf(float f) {
  unsigned int u = __float_as_uint(f);
  u += 0x7fff + ((u >> 16) & 1);  // RNE (no NaN inputs here)
  return (unsigned short)(u >> 16);
}

// async global->LDS, 16B per lane; LDS dest = wave-uniform base + lane*16
__device__ __forceinline__ void gl_lds16(const void* g, void* l) {
  __builtin_amdgcn_global_load_lds(
      (const __attribute__((address_space(1))) unsigned int*)g,
      (__attribute__((address_space(3))) unsigned int*)l, 16, 0, 0);
}

__device__ __forceinline__ int wave_incl_scan(int v, int lane) {
#pragma unroll
  for (int d = 1; d < 64; d <<= 1) {
    int t = __shfl_up(v, d);
    if (lane >= d) v += t;
  }
  return v;
}

// ---------------- CSR build (bucketed; no fine-grained global atomics) ----------------
#define NBK 196      // ceil(100000 / 512) buckets of 512 nodes
#define CHUNK 4096

// coarse bucket histogram (blocks < CBn) + weight-transpose prep (blocks >= CBn).
// Prep path: Wt[n][k] bf16 from W[k][n] fp32 (6 matrices), no LDS, no barriers shared
// with the histogram path (branch is blockIdx-uniform). bcount is zeroed by a
// hipMemsetAsync ordered before this dispatch.
__global__ __launch_bounds__(256) void k_bhistP(const int* __restrict__ dst, int E,
                                                int* __restrict__ bcount, int CBn,
                                                const float* __restrict__ W1,
                                                const float* __restrict__ W2,
                                                unsigned short* __restrict__ Wt) {
  __shared__ int cnt[NBK];
  if ((int)blockIdx.x >= CBn) {
    int b = (int)blockIdx.x - CBn;  // 0..5 : layer = b>>1, (b&1)==0 -> W1 else W2
    const float* W = (b & 1) ? (W2 + (size_t)(b >> 1) * DD) : (W1 + (size_t)(b >> 1) * DD);
    unsigned short* O = Wt + (size_t)b * DD;
    for (int i = threadIdx.x; i < DD; i += 256) {
      int n = i >> 7, k = i & 127;
      O[n * D + k] = f2bf(W[k * D + n]);  // writes coalesced; strided reads stay in L2
    }
    return;
  }
  const int tid = threadIdx.x;
  for (int i = tid; i < NBK; i += 256) cnt[i] = 0;
  __syncthreads();
  const int e0 = blockIdx.x * CHUNK;
  const int emax = min(e0 + CHUNK, E);
  for (int e = e0 + tid; e < emax; e += 256)
    atomicAdd(&cnt[((unsigned)dst[e]) >> 9], 1);
  __syncthreads();
  for (int i = tid; i < NBK; i += 256)
    if (cnt[i]) atomicAdd(&bcount[i], cnt[i]);
}

// pass A: scatter packed (src<<9 | dst&511) into bucket segments as contiguous runs.
// bucket_base scan computed locally per block.
__global__ __launch_bounds__(256) void k_binA(const int* __restrict__ src,
                                              const int* __restrict__ dst, int E,
                                              const int* __restrict__ bcount,
                                              int* __restrict__ bcursor,
                                              int* __restrict__ pairbuf) {
  __shared__ int cnt[NBK];
  __shared__ int base[NBK];
  __shared__ int bb[NBK];  // local exclusive scan of bcount
  __shared__ int ws4[4];
  const int tid = threadIdx.x;
  const int e0 = blockIdx.x * CHUNK;
  const int emax = min(e0 + CHUNK, E);
  for (int i = tid; i < NBK; i += 256) cnt[i] = 0;
  {
    int lane = tid & 63, w = tid >> 6;
    int v = (tid < NBK) ? bcount[tid] : 0;
    int s = wave_incl_scan(v, lane);
    if (lane == 63) ws4[w] = s;
    __syncthreads();
    if (tid < NBK) {
      int off = 0;
      for (int k = 0; k < w; k++) off += ws4[k];
      bb[tid] = off + s - v;
    }
  }
  __syncthreads();
  for (int e = e0 + tid; e < emax; e += 256)
    atomicAdd(&cnt[((unsigned)dst[e]) >> 9], 1);
  __syncthreads();
  for (int i = tid; i < NBK; i += 256) {
    int c = cnt[i];
    int b = 0;
    if (c) b = atomicAdd(&bcursor[i], c) + bb[i];
    base[i] = b;
    cnt[i] = 0;
  }
  __syncthreads();
  for (int e = e0 + tid; e < emax; e += 256) {
    int d = dst[e];
    int bk = ((unsigned)d) >> 9;
    int pos = base[bk] + atomicAdd(&cnt[bk], 1);
    pairbuf[pos] = (src[e] << 9) | (d & 511);  // src<2^17, fits in 26 bits
  }
}

// pass B: one block owns one bucket. Per-node degrees + local scan in LDS, row_ptr
// coalesced, col scattered inside LDS and dumped coalesced.
#define SEG_CAP 12800  // mean seg 8192, sigma ~91 -> cap is +50 sigma
__global__ __launch_bounds__(256) void k_binB(const int* __restrict__ pairbuf,
                                              const int* __restrict__ bcount,
                                              int* __restrict__ col,
                                              int* __restrict__ row_ptr, int N) {
  __shared__ int sdeg[512];
  __shared__ int rpl[512];
  __shared__ int cur[512];
  __shared__ int wsum[4];
  __shared__ int wsum2[4];
  __shared__ int stage[SEG_CAP];
  const int tid = threadIdx.x;
  const int lane = tid & 63, wid = tid >> 6;
  const int node0 = blockIdx.x << 9;
  const int nn = min(512, N - node0);
  // start = sum_{i<bid} bcount[i]
  {
    int vv = (tid < (int)blockIdx.x) ? bcount[tid] : 0;
    vv += __shfl_down(vv, 32); vv += __shfl_down(vv, 16);
    vv += __shfl_down(vv, 8);  vv += __shfl_down(vv, 4);
    vv += __shfl_down(vv, 2);  vv += __shfl_down(vv, 1);
    if (lane == 0) wsum2[wid] = vv;
  }
  for (int i = tid; i < 512; i += 256) { sdeg[i] = 0; cur[i] = 0; }
  __syncthreads();
  const int start = wsum2[0] + wsum2[1] + wsum2[2] + wsum2[3];
  const int end = start + bcount[blockIdx.x];
  const int sz = end - start;  // <= SEG_CAP (astronomically certain)
  for (int i = tid; i < sz; i += 256)
    atomicAdd(&sdeg[pairbuf[start + i] & 511], 1);
  __syncthreads();
  int a = sdeg[2 * tid], b = sdeg[2 * tid + 1];
  int v = a + b;
  int s = wave_incl_scan(v, lane);
  if (lane == 63) wsum[wid] = s;
  __syncthreads();
  int off = 0;
  for (int k = 0; k < wid; k++) off += wsum[k];
  int e0l = off + s - v;
  rpl[2 * tid] = e0l;
  rpl[2 * tid + 1] = e0l + a;
  __syncthreads();
  for (int i = tid; i < nn; i += 256) row_ptr[node0 + i] = start + rpl[i];
  if (blockIdx.x == gridDim.x - 1 && tid == 0) row_ptr[N] = end;
  for (int i = tid; i < sz; i += 256) {
    int pk = pairbuf[start + i];  // coalesced read
    int d = pk & 511;
    int pos = rpl[d] + atomicAdd(&cur[d], 1);
    if (pos < SEG_CAP) stage[pos] = (int)(((unsigned)pk) >> 9);
  }
  __syncthreads();
  for (int i = tid; i < sz; i += 256) col[start + i] = stage[i];  // coalesced write
}

// ------------- aggregation (bf16 in/out): H[i] = relu(Y[i] + sum_j Y[j] + b) -------------
// one wave per node (proven 62.5us @ 3.49 TB/s counted = the random-gather throughput
// ceiling; FETCH 188MB ~= the L2-capacity floor ~176MB. R3 lesson: never co-locate with
// MFMA tiles — gather throughput scales with resident waves).
__global__ __launch_bounds__(256) void k_agg(const unsigned short* __restrict__ Y,
                                             const int* __restrict__ row_ptr,
                                             const int* __restrict__ col,
                                             const float* __restrict__ bias,
                                             unsigned short* __restrict__ H, int N) {
  int wid = (blockIdx.x * 256 + threadIdx.x) >> 6;  // node
  int lane = threadIdx.x & 63;
  if (wid >= N) return;
  const unsigned int* Yu = (const unsigned int*)Y;
  unsigned int sv = Yu[(size_t)wid * 64 + lane];
  float2 bv = ((const float2*)bias)[lane];
  float ax = bv.x + __uint_as_float(sv << 16);
  float ay = bv.y + __uint_as_float(sv & 0xffff0000u);
  int rs = row_ptr[wid], re = row_ptr[wid + 1];
  int dcap = min(re - rs, 64);
  int cv = (lane < dcap) ? col[rs + lane] : 0;  // one coalesced read of the whole list
  int j = 0;
  for (; j + 8 <= dcap; j += 8) {
    int s0 = __shfl(cv, j + 0), s1 = __shfl(cv, j + 1);
    int s2 = __shfl(cv, j + 2), s3 = __shfl(cv, j + 3);
    int s4 = __shfl(cv, j + 4), s5 = __shfl(cv, j + 5);
    int s6 = __shfl(cv, j + 6), s7 = __shfl(cv, j + 7);
    unsigned int v0 = Yu[(size_t)s0 * 64 + lane];
    unsigned int v1 = Yu[(size_t)s1 * 64 + lane];
    unsigned int v2 = Yu[(size_t)s2 * 64 + lane];
    unsigned int v3 = Yu[(size_t)s3 * 64 + lane];
    unsigned int v4 = Yu[(size_t)s4 * 64 + lane];
    unsigned int v5 = Yu[(size_t)s5 * 64 + lane];
    unsigned int v6 = Yu[(size_t)s6 * 64 + lane];
    unsigned int v7 = Yu[(size_t)s7 * 64 + lane];
    ax += ((__uint_as_float(v0 << 16) + __uint_as_float(v1 << 16)) +
           (__uint_as_float(v2 << 16) + __uint_as_float(v3 << 16))) +
          ((__uint_as_float(v4 << 16) + __uint_as_float(v5 << 16)) +
           (__uint_as_float(v6 << 16) + __uint_as_float(v7 << 16)));
    ay += ((__uint_as_float(v0 & 0xffff0000u) + __uint_as_float(v1 & 0xffff0000u)) +
           (__uint_as_float(v2 & 0xffff0000u) + __uint_as_float(v3 & 0xffff0000u))) +
          ((__uint_as_float(v4 & 0xffff0000u) + __uint_as_float(v5 & 0xffff0000u)) +
           (__uint_as_float(v6 & 0xffff0000u) + __uint_as_float(v7 & 0xffff0000u)));
  }
  for (; j < dcap; j++) {
    int s = __shfl(cv, j);
    unsigned int v = Yu[(size_t)s * 64 + lane];
    ax += __uint_as_float(v << 16);
    ay += __uint_as_float(v & 0xffff0000u);
  }
  for (int t = rs + 64; t < re; t++) {  // deg>64 never happens statistically
    unsigned int v = Yu[(size_t)col[t] * 64 + lane];
    ax += __uint_as_float(v << 16);
    ay += __uint_as_float(v & 0xffff0000u);
  }
  ax = fmaxf(ax, 0.f);
  ay = fmaxf(ay, 0.f);
  ((unsigned int*)H)[(size_t)wid * 64 + lane] =
      ((unsigned int)f2bf(ay) << 16) | f2bf(ax);
}

// ------------- MFMA GEMM: C[M,128] = A[M,128] @ W^T (+bias)(+relu) -------------
// One 64-row tile per block, 256 threads = 4 waves (2x2), wave = 32 rows x 64 cols.
// LDS layout: row-major 256B rows, 16B chunks XOR-swizzled (physical p = logical ^ (row&15)).
template <bool A_FP32, bool OUT_FP32>
__global__ __launch_bounds__(256) void k_gemm(const void* __restrict__ Ain,
                                              const unsigned short* __restrict__ Wt,
                                              const float* __restrict__ bias,
                                              void* __restrict__ Cout, int M, int relu) {
  __shared__ __align__(16) unsigned short As[64 * 128];
  __shared__ __align__(16) unsigned short Bs[128 * 128];
  const int tid = threadIdx.x;
  const int wid = tid >> 6, lane = tid & 63;
  const int R0 = blockIdx.x * 64;

#pragma unroll
  for (int g = 0; g < 8; g++) {
    int flat = g * 256 + tid;
    int n = flat >> 4, p = flat & 15;
    int l = p ^ (n & 15);
    gl_lds16(Wt + (size_t)n * D + l * 8, &Bs[(size_t)(g * 256 + wid * 64) * 8]);
  }
  if (A_FP32) {
    const float* A = (const float*)Ain;
#pragma unroll
    for (int g = 0; g < 4; g++) {
      int flat = g * 256 + tid;
      int row = flat >> 4, p = flat & 15;
      int l = p ^ (row & 15);
      float4 a0 = make_float4(0.f, 0.f, 0.f, 0.f), a1 = a0;
      if (R0 + row < M) {
        a0 = *(const float4*)(A + (size_t)(R0 + row) * D + l * 8);
        a1 = *(const float4*)(A + (size_t)(R0 + row) * D + l * 8 + 4);
      }
      ushort4 v0, v1;
      v0.x = f2bf(a0.x); v0.y = f2bf(a0.y); v0.z = f2bf(a0.z); v0.w = f2bf(a0.w);
      v1.x = f2bf(a1.x); v1.y = f2bf(a1.y); v1.z = f2bf(a1.z); v1.w = f2bf(a1.w);
      *(ushort4*)&As[row * D + p * 8] = v0;
      *(ushort4*)&As[row * D + p * 8 + 4] = v1;
    }
  } else {
    const unsigned short* A = (const unsigned short*)Ain;
#pragma unroll
    for (int g = 0; g < 4; g++) {
      int flat = g * 256 + tid;
      int row = flat >> 4, p = flat & 15;
      int l = p ^ (row & 15);
      // rows >= M read garbage from adjacent ws buffers (safe); their outputs unstored
      gl_lds16(A + (size_t)(R0 + row) * D + l * 8, &As[(size_t)(g * 256 + wid * 64) * 8]);
    }
  }
  __syncthreads();  // drains global_load_lds (vmcnt) + LDS writes

  const int wr = wid >> 1, wc = wid & 1;
  const int lm = lane & 15, lq = lane >> 4;
  f32x4 acc[2][4];
#pragma unroll
  for (int i = 0; i < 2; i++)
#pragma unroll
    for (int j = 0; j < 4; j++) acc[i][j] = f32x4{0.f, 0.f, 0.f, 0.f};

#pragma unroll
  for (int kc = 0; kc < 4; kc++) {
    const int pc = (kc * 4 + lq) ^ lm;
    bf16x8 af[2], bfr[4];
#pragma unroll
    for (int i = 0; i < 2; i++)
      af[i] = *(const bf16x8*)&As[(wr * 32 + i * 16 + lm) * D + pc * 8];
#pragma unroll
    for (int j = 0; j < 4; j++)
      bfr[j] = *(const bf16x8*)&Bs[(wc * 64 + j * 16 + lm) * D + pc * 8];
#pragma unroll
    for (int i = 0; i < 2; i++)
#pragma unroll
      for (int j = 0; j < 4; j++)
        acc[i][j] = __builtin_amdgcn_mfma_f32_16x16x32_bf16(af[i], bfr[j], acc[i][j], 0, 0, 0);
  }

  float bv[4];
#pragma unroll
  for (int j = 0; j < 4; j++) bv[j] = bias ? bias[wc * 64 + j * 16 + lm] : 0.f;
#pragma unroll
  for (int i = 0; i < 2; i++) {
#pragma unroll
    for (int reg = 0; reg < 4; reg++) {
      const int gr = R0 + wr * 32 + i * 16 + lq * 4 + reg;
      if (gr < M) {
#pragma unroll
        for (int j = 0; j < 4; j++) {
          const int gc = wc * 64 + j * 16 + lm;
          float v = acc[i][j][reg] + bv[j];
          if (relu) v = fmaxf(v, 0.f);
          if (OUT_FP32)
            ((float*)Cout)[(size_t)gr * D + gc] = v;
          else
            ((unsigned short*)Cout)[(size_t)gr * D + gc] = f2bf(v);
        }
      }
    }
  }
}

// ---- fused GEMM pair: C = relu(A@W2t^T + b2) @ W1t^T, all bf16 in/out ----
// Stage1 result bounces through LDS (As reused) instead of a 51.2MB global round-trip.
__global__ __launch_bounds__(256) void k_gemm2(const unsigned short* __restrict__ Ain,
                                               const unsigned short* __restrict__ W2t,
                                               const unsigned short* __restrict__ W1t,
                                               const float* __restrict__ b2,
                                               unsigned short* __restrict__ Cout, int M) {
  __shared__ __align__(16) unsigned short As[64 * 128];
  __shared__ __align__(16) unsigned short Bs[128 * 128];
  const int tid = threadIdx.x;
  const int wid = tid >> 6, lane = tid & 63;
  const int R0 = blockIdx.x * 64;

#pragma unroll
  for (int g = 0; g < 8; g++) {
    int flat = g * 256 + tid;
    int n = flat >> 4, p = flat & 15;
    int l = p ^ (n & 15);
    gl_lds16(W2t + (size_t)n * D + l * 8, &Bs[(size_t)(g * 256 + wid * 64) * 8]);
  }
#pragma unroll
  for (int g = 0; g < 4; g++) {
    int flat = g * 256 + tid;
    int row = flat >> 4, p = flat & 15;
    int l = p ^ (row & 15);
    gl_lds16(Ain + (size_t)(R0 + row) * D + l * 8, &As[(size_t)(g * 256 + wid * 64) * 8]);
  }
  __syncthreads();

  const int wr = wid >> 1, wc = wid & 1;
  const int lm = lane & 15, lq = lane >> 4;
  f32x4 acc[2][4];
#pragma unroll
  for (int i = 0; i < 2; i++)
#pragma unroll
    for (int j = 0; j < 4; j++) acc[i][j] = f32x4{0.f, 0.f, 0.f, 0.f};
#pragma unroll
  for (int kc = 0; kc < 4; kc++) {
    const int pc = (kc * 4 + lq) ^ lm;
    bf16x8 af[2], bfr[4];
#pragma unroll
    for (int i = 0; i < 2; i++)
      af[i] = *(const bf16x8*)&As[(wr * 32 + i * 16 + lm) * D + pc * 8];
#pragma unroll
    for (int j = 0; j < 4; j++)
      bfr[j] = *(const bf16x8*)&Bs[(wc * 64 + j * 16 + lm) * D + pc * 8];
#pragma unroll
    for (int i = 0; i < 2; i++)
#pragma unroll
      for (int j = 0; j < 4; j++)
        acc[i][j] = __builtin_amdgcn_mfma_f32_16x16x32_bf16(af[i], bfr[j], acc[i][j], 0, 0, 0);
  }
  __syncthreads();  // all waves done reading As & Bs

  // re-stage Bs <- W1t (in flight across epilogue1; drained by next barrier)
#pragma unroll
  for (int g = 0; g < 8; g++) {
    int flat = g * 256 + tid;
    int n = flat >> 4, p = flat & 15;
    int l = p ^ (n & 15);
    gl_lds16(W1t + (size_t)n * D + l * 8, &Bs[(size_t)(g * 256 + wid * 64) * 8]);
  }
  // epilogue1: X = relu(acc + b2) -> bf16 into As (same XOR-swizzled layout)
  {
    float bv[4];
#pragma unroll
    for (int j = 0; j < 4; j++) bv[j] = b2[wc * 64 + j * 16 + lm];
#pragma unroll
    for (int i = 0; i < 2; i++) {
#pragma unroll
      for (int reg = 0; reg < 4; reg++) {
        const int row = wr * 32 + i * 16 + lq * 4 + reg;
#pragma unroll
        for (int j = 0; j < 4; j++) {
          const int gc = wc * 64 + j * 16 + lm;
          float v = fmaxf(acc[i][j][reg] + bv[j], 0.f);
          As[row * D + (((gc >> 3) ^ (row & 15)) << 3) + (gc & 7)] = f2bf(v);
        }
      }
    }
  }
  __syncthreads();  // drains gl_lds (vmcnt) + ds_writes

  f32x4 acc2[2][4];
#pragma unroll
  for (int i = 0; i < 2; i++)
#pragma unroll
    for (int j = 0; j < 4; j++) acc2[i][j] = f32x4{0.f, 0.f, 0.f, 0.f};
#pragma unroll
  for (int kc = 0; kc < 4; kc++) {
    const int pc = (kc * 4 + lq) ^ lm;
    bf16x8 af[2], bfr[4];
#pragma unroll
    for (int i = 0; i < 2; i++)
      af[i] = *(const bf16x8*)&As[(wr * 32 + i * 16 + lm) * D + pc * 8];
#pragma unroll
    for (int j = 0; j < 4; j++)
      bfr[j] = *(const bf16x8*)&Bs[(wc * 64 + j * 16 + lm) * D + pc * 8];
#pragma unroll
    for (int i = 0; i < 2; i++)
#pragma unroll
      for (int j = 0; j < 4; j++)
        acc2[i][j] = __builtin_amdgcn_mfma_f32_16x16x32_bf16(af[i], bfr[j], acc2[i][j], 0, 0, 0);
  }
  // epilogue2: Y' bf16 to global (no bias, no relu)
#pragma unroll
  for (int i = 0; i < 2; i++) {
#pragma unroll
    for (int reg = 0; reg < 4; reg++) {
      const int gr = R0 + wr * 32 + i * 16 + lq * 4 + reg;
      if (gr < M) {
#pragma unroll
        for (int j = 0; j < 4; j++) {
          const int gc = wc * 64 + j * 16 + lm;
          Cout[(size_t)gr * D + gc] = f2bf(acc2[i][j][reg]);
        }
      }
    }
  }
}

// ---------------- launch ----------------
// GIN eps=0: out = MLP(x + sum_src x). Linearity: GEMM(W1) first, then aggregate
// (+b1,relu), then fused GEMM pair at layer boundaries. 11 enqueues (memset + 10).
extern "C" void kernel_launch(void* const* d_in, const int* in_sizes, int n_in,
                              void* d_out, int out_size, void* d_ws, size_t ws_size,
                              hipStream_t stream) {
  const float* x  = (const float*)d_in[0];
  const int*   ei = (const int*)d_in[1];
  const float* W1 = (const float*)d_in[2];
  const float* b1 = (const float*)d_in[3];
  const float* W2 = (const float*)d_in[4];
  const float* b2 = (const float*)d_in[5];
  const int N = in_sizes[0] / D;  // 100000
  const int E = in_sizes[1] / 2;  // 1600000
  const int* src = ei;
  const int* dst = ei + E;

  // workspace: Wt (192KB) + 2 bf16 node buffers (N+1 rows) + CSR (~7MB).
  // pairbuf aliases bufB (dead before bufB first written).
  char* ws = (char*)d_ws;
  unsigned short* Wt   = (unsigned short*)ws;                 // 6*128*128 bf16
  unsigned short* bufA = Wt + 6 * DD;
  unsigned short* bufB = bufA + (size_t)(N + 1) * D;
  int* pairbuf = (int*)bufB;
  int* row_ptr = (int*)(bufB + (size_t)(N + 1) * D);
  int* colv    = row_ptr + (N + 1);
  int* bcount  = colv + E;          // 256 ints
  int* bcursor = bcount + 256;      // 256 ints (contiguous with bcount: zeroed together)
  float* OUT   = (float*)d_out;

  const int CB  = (E + CHUNK - 1) / CHUNK;     // 391 chunk blocks
  const int GB  = (N + 63) / 64;               // 1563 GEMM tiles
  const int AB  = (N + 3) / 4;                 // agg: 4 waves/block, 1 node/wave
  const int BKB = (N + 511) / 512;             // 196 buckets

  hipMemsetAsync(bcount, 0, 512 * sizeof(int), stream);  // bcount + bcursor (R1-proven)
  k_bhistP<<<CB + 6, 256, 0, stream>>>(dst, E, bcount, CB, W1, W2, Wt);
  k_binA<<<CB, 256, 0, stream>>>(src, dst, E, bcount, bcursor, pairbuf);
  k_binB<<<BKB, 256, 0, stream>>>(pairbuf, bcount, colv, row_ptr, N);

  // layer 0 front GEMM: Y0 = x @ W1_0
  k_gemm<true, false><<<GB, 256, 0, stream>>>(x, Wt + 0 * DD, nullptr, bufA, N, 0);
  k_agg<<<AB, 256, 0, stream>>>(bufA, row_ptr, colv, b1, bufB, N);
  // boundary 0: relu(h0@W2_0+b2_0) @ W1_1
  k_gemm2<<<GB, 256, 0, stream>>>(bufB, Wt + 1 * DD, Wt + 2 * DD, b2, bufA, N);
  k_agg<<<AB, 256, 0, stream>>>(bufA, row_ptr, colv, b1 + D, bufB, N);
  // boundary 1
  k_gemm2<<<GB, 256, 0, stream>>>(bufB, Wt + 3 * DD, Wt + 4 * DD, b2 + D, bufA, N);
  k_agg<<<AB, 256, 0, stream>>>(bufA, row_ptr, colv, b1 + 2 * D, bufB, N);
  // final GEMM
  k_gemm<false, true><<<GB, 256, 0, stream>>>(bufB, Wt + 5 * DD, b2 + 2 * D, OUT, N, 0);
  (void)n_in; (void)out_size; (void)ws_size;
}